// Round 1
// baseline (385.400 us; speedup 1.0000x reference)
//
#include <hip/hip_runtime.h>
#include <hip/hip_cooperative_groups.h>
#include <math.h>

namespace cg = cooperative_groups;

#define B_ 2
#define L_ 5000
#define E_ 20
#define H_ 5
#define FF_ 120
#define DEC_ 40
#define K_ 50
#define PAD_ 25
#define SCALE 0.22360679774997896f  // 1/sqrt(E)

#define NM 35                    // symmetric monomials deg<=3 in 4 vars
#define MST2 180                 // per-(b,h): 5 c-slots x 36 (35 used + pad)
#define MLAYER (B_ * H_ * MST2)  // 1800 floats per layer

// ---- cooperative megakernel geometry ----
#define BLK_ 512                 // 64 positions x 8 parts; part is wave-uniform
#define NPOS 64
#define TPB_ 79                  // ceil(L/64) tiles per batch
#define GRID_ (B_ * TPB_)        // 158 blocks <= 256 CUs -> 1 block/CU co-resident
#define MCH 512                  // keys per moment chunk
#define NCHU 10                  // ceil(L/512); 2*5*10 = 100 units <= 158 blocks

// ---- fallback (original) geometry ----
#define ACH 128
#define NCH 40

typedef float v2f __attribute__((ext_vector_type(2)));
__device__ __forceinline__ v2f vsplat(float x) { v2f r; r.x = x; r.y = x; return r; }

// monomial index tables; slot 4 is the constant-1 slot.
__constant__ int TD[NM] = {4, 0,1,2,3, 0,0,0,0,1,1,1,2,2,3,
                           0,0,0,0,0,0,0,0,0,0,1,1,1,1,1,1,2,2,2,3};
__constant__ int TE[NM] = {4, 4,4,4,4, 0,1,2,3,1,2,3,2,3,3,
                           0,0,0,0,1,1,1,2,2,3,1,1,1,2,2,3,2,2,3,3};
__constant__ int TF[NM] = {4, 4,4,4,4, 4,4,4,4,4,4,4,4,4,4,
                           0,1,2,3,1,2,3,2,3,3,1,2,3,2,3,3,2,3,3,3};

__device__ __forceinline__ void mono36(const float x[4], float m[36]) {
  int idx = 0;
  m[idx++] = 1.f;
#pragma unroll
  for (int d = 0; d < 4; d++) m[idx++] = x[d];
#pragma unroll
  for (int d = 0; d < 4; d++)
#pragma unroll
    for (int e = d; e < 4; e++) m[idx++] = x[d] * x[e];
#pragma unroll
  for (int d = 0; d < 4; d++)
#pragma unroll
    for (int e = d; e < 4; e++)
#pragma unroll
      for (int f = e; f < 4; f++) m[idx++] = x[d] * x[e] * x[f];
  m[35] = 0.f;
}

__device__ __forceinline__ void qcoef(float* mq) {
  const float S = 1.f / 6.f;
  mq[5]  *= 0.5f; mq[9]  *= 0.5f; mq[12] *= 0.5f; mq[14] *= 0.5f;
  mq[15] *= S;    mq[25] *= S;    mq[31] *= S;    mq[34] *= S;
  mq[16] *= 0.5f; mq[17] *= 0.5f; mq[18] *= 0.5f; mq[19] *= 0.5f;
  mq[22] *= 0.5f; mq[24] *= 0.5f; mq[26] *= 0.5f; mq[27] *= 0.5f;
  mq[28] *= 0.5f; mq[30] *= 0.5f; mq[32] *= 0.5f; mq[33] *= 0.5f;
}

#define DOT20G(res, W, row, vec)                                     \
  {                                                                  \
    const float4* Wr = (const float4*)((W) + (row) * 20);            \
    float c0 = 0.f, c1 = 0.f, c2 = 0.f, c3 = 0.f;                    \
    _Pragma("unroll") for (int g5 = 0; g5 < 5; g5++) {               \
      float4 w4 = Wr[g5];                                            \
      c0 += w4.x * vec[g5 * 4 + 0];                                  \
      c1 += w4.y * vec[g5 * 4 + 1];                                  \
      c2 += w4.z * vec[g5 * 4 + 2];                                  \
      c3 += w4.w * vec[g5 * 4 + 3];                                  \
    }                                                                \
    res += (c0 + c1) + (c2 + c3);                                    \
  }

#define DOT40G(res, W, row, vec)                                     \
  {                                                                  \
    const float4* Wr = (const float4*)((W) + (row) * 40);            \
    float c0 = 0.f, c1 = 0.f, c2 = 0.f, c3 = 0.f;                    \
    _Pragma("unroll") for (int g5 = 0; g5 < 10; g5++) {              \
      float4 w4 = Wr[g5];                                            \
      c0 += w4.x * vec[g5 * 4 + 0];                                  \
      c1 += w4.y * vec[g5 * 4 + 1];                                  \
      c2 += w4.z * vec[g5 * 4 + 2];                                  \
      c3 += w4.w * vec[g5 * 4 + 3];                                  \
    }                                                                \
    res += (c0 + c1) + (c2 + c3);                                    \
  }

// LDS: union of moment-phase staging and fused-phase hand-off buffers.
struct SUf {
  float4 so4[NPOS][7];   // [p][head], padded
  float stv[NPOS * E_];  // [p][20]
  float sc[BLK_ * E_];   // [tid][20]; decoder reuses as p*101
};
union __align__(16) SU {
  float kvs[10][MCH + 2];  // 20.6 KB
  SUf f;                   // 53.2 KB
};

// ---------------------------------------------------------------------------
// Fused layer phase (verbatim math from the proven fused_kernel, re-indexed
// for 64 positions x 8 parts; part = tid>>6 is wave-uniform).
// ---------------------------------------------------------------------------
__device__ __forceinline__ void fused_phase(
    bool last, int tid, int p, int part, int fb, int pos, bool act,
    const float* __restrict__ M, const float* __restrict__ Wq,
    const float* __restrict__ Wc, const float* __restrict__ bc,
    const float* __restrict__ lnAg, const float* __restrict__ lnAb,
    const float* __restrict__ W1, const float* __restrict__ b1,
    const float* __restrict__ W2t, const float* __restrict__ b2,
    const float* __restrict__ lnBg, const float* __restrict__ lnBb,
    float* __restrict__ hbuf,
    const float* __restrict__ f1w, const float* __restrict__ f1b,
    const float* __restrict__ f2w, const float* __restrict__ f2b,
    const float* __restrict__ f3w, const float* __restrict__ f3b,
    const float* __restrict__ f4w, const float* __restrict__ f4b,
    float* __restrict__ out, SUf* F) {
  // residual vector (constant-indexed only -> stays in VGPRs)
  float hv[E_];
#pragma unroll
  for (int e4 = 0; e4 < 5; e4++) {
    float4 h4 = *(const float4*)(hbuf + pos * E_ + e4 * 4);
    hv[e4 * 4 + 0] = h4.x; hv[e4 * 4 + 1] = h4.y;
    hv[e4 * 4 + 2] = h4.z; hv[e4 * 4 + 3] = h4.w;
  }

  // ---- A: attention eval, head = part (parts 5-7 idle) ----
  if (part < H_) {
    float4 qsrc = *(const float4*)(hbuf + pos * E_ + part * 4);
    float q[4];
#pragma unroll
    for (int d = 0; d < 4; d++) {
      q[d] = (Wq[d * 4 + 0] * qsrc.x + Wq[d * 4 + 1] * qsrc.y +
              Wq[d * 4 + 2] * qsrc.z + Wq[d * 4 + 3] * qsrc.w) *
             SCALE;
    }
    float mq[36];
    mono36(q, mq);
    qcoef(mq);
    const float* Mb = M + (fb * H_ + part) * MST2;
    float oc[5];
#pragma unroll
    for (int c = 0; c < 5; c++) {
      const float4* Mr = (const float4*)(Mb + c * 36);
      float a0 = 0.f, a1 = 0.f, a2 = 0.f, a3 = 0.f;
#pragma unroll
      for (int g = 0; g < 9; g++) {
        float4 w4 = Mr[g];
        a0 += w4.x * mq[g * 4 + 0];
        a1 += w4.y * mq[g * 4 + 1];
        a2 += w4.z * mq[g * 4 + 2];
        a3 += w4.w * mq[g * 4 + 3];
      }
      oc[c] = (a0 + a1) + (a2 + a3);
    }
    float inv = 1.f / oc[4];
    F->so4[p][part] =
        make_float4(oc[0] * inv, oc[1] * inv, oc[2] * inv, oc[3] * inv);
  }
  __syncthreads();

  // ---- B: Wc rows per part + bias -> stv ----
  float o[E_];
#pragma unroll
  for (int hh = 0; hh < H_; hh++) {
    float4 o4 = F->so4[p][hh];
    o[hh * 4 + 0] = o4.x; o[hh * 4 + 1] = o4.y;
    o[hh * 4 + 2] = o4.z; o[hh * 4 + 3] = o4.w;
  }
  int r0 = (part < 4) ? part * 3 : 12 + (part - 4) * 2;
  int nr = (part < 4) ? 3 : 2;
  for (int r = 0; r < nr; r++) {
    int row = r0 + r;
    float acc = bc[row];
    DOT20G(acc, Wc, row, o);
    F->stv[p * E_ + row] = acc;
  }
  __syncthreads();

  // ---- C: add residual, LN_A (redundant per thread) ----
  float tv[E_];
#pragma unroll
  for (int e4 = 0; e4 < 5; e4++) {
    float4 t4 = *(const float4*)(F->stv + p * E_ + e4 * 4);
    tv[e4 * 4 + 0] = t4.x + hv[e4 * 4 + 0];
    tv[e4 * 4 + 1] = t4.y + hv[e4 * 4 + 1];
    tv[e4 * 4 + 2] = t4.z + hv[e4 * 4 + 2];
    tv[e4 * 4 + 3] = t4.w + hv[e4 * 4 + 3];
  }
  float mu = 0.f;
#pragma unroll
  for (int e = 0; e < E_; e++) mu += tv[e];
  mu *= (1.f / E_);
  float var = 0.f;
#pragma unroll
  for (int e = 0; e < E_; e++) { float d = tv[e] - mu; var += d * d; }
  var *= (1.f / E_);
  float rs = rsqrtf(var + 1e-5f);
  float h1[E_];
#pragma unroll
  for (int e = 0; e < E_; e++) h1[e] = (tv[e] - mu) * rs * lnAg[e] + lnAb[e];

  // ---- D: FFN, 15 rows per part ----
  float g2p[E_];
#pragma unroll
  for (int e = 0; e < E_; e++) g2p[e] = 0.f;
  int jf0 = part * (FF_ / 8);
#pragma unroll
  for (int jj = 0; jj < FF_ / 8; jj++) {
    int j = jf0 + jj;
    float f = b1[j];
    DOT20G(f, W1, j, h1);
    f = fmaxf(f, 0.f);
    const float4* Wr = (const float4*)(W2t + j * 20);
#pragma unroll
    for (int g = 0; g < 5; g++) {
      float4 w4 = Wr[g];
      g2p[g * 4 + 0] += w4.x * f;
      g2p[g * 4 + 1] += w4.y * f;
      g2p[g * 4 + 2] += w4.z * f;
      g2p[g * 4 + 3] += w4.w * f;
    }
  }
  float4* scw = (float4*)(F->sc + tid * E_);
#pragma unroll
  for (int g = 0; g < 5; g++)
    scw[g] = make_float4(g2p[g * 4], g2p[g * 4 + 1], g2p[g * 4 + 2],
                         g2p[g * 4 + 3]);
  __syncthreads();

  // ---- E: reduce 8 partials + b2 + residual(h1), LN_B ----
  float g2[E_];
#pragma unroll
  for (int e = 0; e < E_; e++) g2[e] = b2[e] + h1[e];
#pragma unroll
  for (int pp = 0; pp < 8; pp++) {
    const float4* r = (const float4*)(F->sc + (pp * NPOS + p) * E_);
#pragma unroll
    for (int g = 0; g < 5; g++) {
      float4 v4 = r[g];
      g2[g * 4 + 0] += v4.x; g2[g * 4 + 1] += v4.y;
      g2[g * 4 + 2] += v4.z; g2[g * 4 + 3] += v4.w;
    }
  }
  float mu2 = 0.f;
#pragma unroll
  for (int e = 0; e < E_; e++) mu2 += g2[e];
  mu2 *= (1.f / E_);
  float var2 = 0.f;
#pragma unroll
  for (int e = 0; e < E_; e++) { float d = g2[e] - mu2; var2 += d * d; }
  var2 *= (1.f / E_);
  float rs2 = rsqrtf(var2 + 1e-5f);
  float hn[E_];
#pragma unroll
  for (int e = 0; e < E_; e++) hn[e] = (g2[e] - mu2) * rs2 * lnBg[e] + lnBb[e];

  if (!last) {
    if (act && part == 0) {
#pragma unroll
      for (int e4 = 0; e4 < 5; e4++) {
        *(float4*)(hbuf + pos * E_ + e4 * 4) =
            make_float4(hn[e4 * 4], hn[e4 * 4 + 1], hn[e4 * 4 + 2],
                        hn[e4 * 4 + 3]);
      }
    }
  } else {
    __syncthreads();  // reduce reads done before reusing sc
#pragma unroll
    for (int j = 0; j < DEC_ / 8; j++) {
      int jj = part * (DEC_ / 8) + j;
      float a = f1b[jj];
      DOT20G(a, f1w, jj, hn);
      F->sc[p * 101 + jj] = fmaxf(a, 0.f);
    }
    __syncthreads();
    float d1[DEC_];
#pragma unroll
    for (int k = 0; k < DEC_; k++) d1[k] = F->sc[p * 101 + k];
#pragma unroll
    for (int j = 0; j < DEC_ / 8; j++) {
      int jj = part * (DEC_ / 8) + j;
      float a = f2b[jj];
      DOT40G(a, f2w, jj, d1);
      F->sc[p * 101 + 40 + jj] = fmaxf(a, 0.f);
    }
    __syncthreads();
    float d2[DEC_];
#pragma unroll
    for (int k = 0; k < DEC_; k++) d2[k] = F->sc[p * 101 + 40 + k];
    if (part < 5) {
#pragma unroll
      for (int j = 0; j < 4; j++) {
        int ee = part * 4 + j;
        float a = f3b[ee];
        DOT40G(a, f3w, ee, d2);
        F->sc[p * 101 + 80 + ee] = fmaxf(a, 0.f);
      }
    }
    __syncthreads();
    if (act && part == 0) {
      float z = f4b[0];
      const float* dv = F->sc + p * 101 + 80;
      DOT20G(z, f4w, 0, dv);
      out[pos] = 1.f / (1.f + __expf(-z));
    }
  }
}

// ---------------------------------------------------------------------------
// THE megakernel: conv+PE -> 4 x (moments -> fused layer), grid-synced.
// 158 blocks x 512 threads, 1 block/CU guaranteed co-resident.
// ---------------------------------------------------------------------------
__global__ __launch_bounds__(BLK_) void megakernel(
    const float* __restrict__ x, const float* __restrict__ cw,
    const float* __restrict__ Wv, const float* __restrict__ Wk,
    const float* __restrict__ Wq, const float* __restrict__ Wc,
    const float* __restrict__ bc, const float* __restrict__ lnAg,
    const float* __restrict__ lnAb, const float* __restrict__ W1,
    const float* __restrict__ b1, const float* __restrict__ W2,
    const float* __restrict__ b2, const float* __restrict__ lnBg,
    const float* __restrict__ lnBb,
    const float* __restrict__ f1w, const float* __restrict__ f1b,
    const float* __restrict__ f2w, const float* __restrict__ f2b,
    const float* __restrict__ f3w, const float* __restrict__ f3b,
    const float* __restrict__ f4w, const float* __restrict__ f4b,
    float* __restrict__ out, float* __restrict__ hbuf,
    float* __restrict__ Mall, float* __restrict__ W2t) {
  __shared__ SU S;
  cg::grid_group gg = cg::this_grid();
  const int tid = threadIdx.x;
  const int bid = blockIdx.x;

  // ---- phase 0: zero all M, transpose W2 (all layers), conv embed + PE ----
  {
    const int stride = GRID_ * BLK_;
    int tg = bid * BLK_ + tid;
    if (tg < 4 * MLAYER) Mall[tg] = 0.f;
    if (tg < 4 * E_ * FF_) {
      int i = tg / (E_ * FF_), r = tg % (E_ * FF_);
      int e = r / FF_, j = r % FF_;
      W2t[i * 2400 + j * E_ + e] = W2[i * 2400 + e * FF_ + j];
    }
    for (int idx = tg; idx < B_ * L_ * E_; idx += stride) {
      int e = idx % E_;
      int bl = idx / E_;
      int b = bl / L_, l = bl % L_;
      const float* xr = x + b * L_;
      const float* wr = cw + e * K_;
      float a0 = 0.f, a1 = 0.f;
#pragma unroll
      for (int k = 0; k < K_; k += 2) {
        int i0 = l + k - PAD_, i1 = i0 + 1;
        float x0 = (i0 >= 0 && i0 < L_) ? xr[i0] : 0.f;
        float x1 = (i1 >= 0 && i1 < L_) ? xr[i1] : 0.f;
        a0 += x0 * wr[k];
        a1 += x1 * wr[k + 1];
      }
      double expo =
          (e & 1) ? (double)(e + 1) / (double)E_ : (double)e / (double)E_;
      double factor = pow(10000.0, -expo);
      double arg = (double)l * factor;
      float pe = (e & 1) ? (float)cos(arg) : (float)sin(arg);
      hbuf[bl * E_ + e] = (a0 + a1) + pe;
    }
  }
  gg.sync();

  const int p = tid & (NPOS - 1);
  const int part = tid >> 6;  // wave-uniform
  const int fb = bid / TPB_;
  const int l = (bid % TPB_) * NPOS + p;
  const bool act = l < L_;
  const int lc = act ? l : L_ - 1;
  const int pos = fb * L_ + lc;

  for (int layer = 0; layer < 4; layer++) {
    // ---- moment phase: 100 units of (bh, 512-key chunk) ----
    if (bid < B_ * H_ * NCHU) {
      int bh = bid / NCHU, chunk = bid % NCHU;
      int mb = bh / H_, hh = bh % H_;
      const float* WkL = Wk + layer * 16;
      const float* WvL = Wv + layer * 16;
      {
        float wk[16], wv[16];
#pragma unroll
        for (int i2 = 0; i2 < 16; i2++) { wk[i2] = WkL[i2]; wv[i2] = WvL[i2]; }
        int j = chunk * MCH + tid;
        bool valid = j < L_;
        int jc = valid ? j : L_ - 1;
        float4 s4 = *(const float4*)(hbuf + (mb * L_ + jc) * E_ + hh * 4);
        float vm = valid ? 1.f : 0.f;
        int t = tid;
        S.kvs[0][t] = wk[0] * s4.x + wk[1] * s4.y + wk[2] * s4.z + wk[3] * s4.w;
        S.kvs[1][t] = wk[4] * s4.x + wk[5] * s4.y + wk[6] * s4.z + wk[7] * s4.w;
        S.kvs[2][t] = wk[8] * s4.x + wk[9] * s4.y + wk[10] * s4.z + wk[11] * s4.w;
        S.kvs[3][t] = wk[12] * s4.x + wk[13] * s4.y + wk[14] * s4.z + wk[15] * s4.w;
        S.kvs[4][t] = 1.f;
        S.kvs[5][t] = (wv[0] * s4.x + wv[1] * s4.y + wv[2] * s4.z + wv[3] * s4.w) * vm;
        S.kvs[6][t] = (wv[4] * s4.x + wv[5] * s4.y + wv[6] * s4.z + wv[7] * s4.w) * vm;
        S.kvs[7][t] = (wv[8] * s4.x + wv[9] * s4.y + wv[10] * s4.z + wv[11] * s4.w) * vm;
        S.kvs[8][t] = (wv[12] * s4.x + wv[13] * s4.y + wv[14] * s4.z + wv[15] * s4.w) * vm;
        S.kvs[9][t] = vm;
      }
      __syncthreads();
      if (tid < 2 * NM * 5) {  // 350 threads: (m,c) x half-range
        int t = tid % (NM * 5);
        int half = tid / (NM * 5);
        int m = t / 5, c = t % 5;
        int sd = TD[m], se = TE[m], sf = TF[m], sv = 5 + c;
        int j0 = half * (MCH / 2);
        v2f acc = vsplat(0.f);
#pragma unroll 4
        for (int j = 0; j < MCH / 2; j += 2) {
          v2f a = *(const v2f*)&S.kvs[sd][j0 + j];
          v2f bq = *(const v2f*)&S.kvs[se][j0 + j];
          v2f cq = *(const v2f*)&S.kvs[sf][j0 + j];
          v2f vv = *(const v2f*)&S.kvs[sv][j0 + j];
          acc += a * bq * cq * vv;
        }
        atomicAdd(&Mall[layer * MLAYER + bh * MST2 + c * 36 + m],
                  acc.x + acc.y);
      }
    }
    gg.sync();

    // ---- fused layer phase ----
    fused_phase(layer == 3, tid, p, part, fb, pos, act,
                Mall + layer * MLAYER, Wq + layer * 16, Wc + layer * 400,
                bc + layer * 20, lnAg + layer * 20, lnAb + layer * 20,
                W1 + layer * 2400, b1 + layer * 120, W2t + layer * 2400,
                b2 + layer * 20, lnBg + layer * 20, lnBb + layer * 20, hbuf,
                f1w, f1b, f2w, f2b, f3w, f3b, f4w, f4b, out, &S.f);
    if (layer < 3) gg.sync();
  }
}

// ===========================================================================
// Fallback path: the original verified 9-kernel pipeline (used only if the
// cooperative launch is rejected, e.g. by graph capture).
// ===========================================================================
__global__ __launch_bounds__(256) void conv_pe_kernel(
    const float* __restrict__ x, const float* __restrict__ w,
    float* __restrict__ hbuf, float* __restrict__ Mall) {
  int tid = blockIdx.x * 256 + threadIdx.x;
  if (tid < 4 * MLAYER) Mall[tid] = 0.f;
  if (tid >= B_ * L_ * E_) return;
  int e = tid % E_;
  int bl = tid / E_;
  int b = bl / L_, l = bl % L_;

  const float* xr = x + b * L_;
  const float* wr = w + e * K_;
  float a0 = 0.f, a1 = 0.f;
#pragma unroll
  for (int k = 0; k < K_; k += 2) {
    int i0 = l + k - PAD_, i1 = i0 + 1;
    float x0 = (i0 >= 0 && i0 < L_) ? xr[i0] : 0.f;
    float x1 = (i1 >= 0 && i1 < L_) ? xr[i1] : 0.f;
    a0 += x0 * wr[k];
    a1 += x1 * wr[k + 1];
  }
  double expo = (e & 1) ? (double)(e + 1) / (double)E_ : (double)e / (double)E_;
  double factor = pow(10000.0, -expo);
  double arg = (double)l * factor;
  float pe = (e & 1) ? (float)cos(arg) : (float)sin(arg);
  hbuf[bl * E_ + e] = (a0 + a1) + pe;
}

__global__ __launch_bounds__(192, 1) void moment_kernel(
    const float* __restrict__ hbuf,
    const float* __restrict__ Wk, const float* __restrict__ Wv,
    const float* __restrict__ W2, float* __restrict__ W2t,
    float* __restrict__ M) {
  __shared__ __align__(16) float kvs[10][ACH + 2];
  int bh = blockIdx.x / NCH;
  int chunk = blockIdx.x % NCH;
  int b = bh / H_, hh = bh % H_;

  if (blockIdx.x == 0) {
    for (int i = threadIdx.x; i < E_ * FF_; i += 192) {
      int e = i / FF_, j = i % FF_;
      W2t[j * E_ + e] = W2[i];
    }
  }

  if (threadIdx.x < ACH) {
    float wk[16], wv[16];
#pragma unroll
    for (int i = 0; i < 16; i++) { wk[i] = Wk[i]; wv[i] = Wv[i]; }
    int j = chunk * ACH + threadIdx.x;
    bool valid = j < L_;
    int jc = valid ? j : (L_ - 1);
    float4 s4 = *(const float4*)(hbuf + (b * L_ + jc) * E_ + hh * 4);
    float vm = valid ? 1.f : 0.f;
    int t = threadIdx.x;
    kvs[0][t] = wk[0] * s4.x + wk[1] * s4.y + wk[2] * s4.z + wk[3] * s4.w;
    kvs[1][t] = wk[4] * s4.x + wk[5] * s4.y + wk[6] * s4.z + wk[7] * s4.w;
    kvs[2][t] = wk[8] * s4.x + wk[9] * s4.y + wk[10] * s4.z + wk[11] * s4.w;
    kvs[3][t] = wk[12] * s4.x + wk[13] * s4.y + wk[14] * s4.z + wk[15] * s4.w;
    kvs[4][t] = 1.f;
    kvs[5][t] = (wv[0] * s4.x + wv[1] * s4.y + wv[2] * s4.z + wv[3] * s4.w) * vm;
    kvs[6][t] = (wv[4] * s4.x + wv[5] * s4.y + wv[6] * s4.z + wv[7] * s4.w) * vm;
    kvs[7][t] = (wv[8] * s4.x + wv[9] * s4.y + wv[10] * s4.z + wv[11] * s4.w) * vm;
    kvs[8][t] = (wv[12] * s4.x + wv[13] * s4.y + wv[14] * s4.z + wv[15] * s4.w) * vm;
    kvs[9][t] = vm;
  }
  __syncthreads();

  int t = threadIdx.x;
  if (t >= NM * 5) return;
  int m = t / 5, c = t % 5;
  int sd = TD[m], se = TE[m], sf = TF[m], sv = 5 + c;
  v2f acc = vsplat(0.f);
#pragma unroll 4
  for (int j = 0; j < ACH; j += 2) {
    v2f a = *(const v2f*)&kvs[sd][j];
    v2f bq = *(const v2f*)&kvs[se][j];
    v2f cq = *(const v2f*)&kvs[sf][j];
    v2f vv = *(const v2f*)&kvs[sv][j];
    acc += a * bq * cq * vv;
  }
  atomicAdd(&M[bh * MST2 + c * 36 + m], acc.x + acc.y);
}

template <int LAST>
__global__ __launch_bounds__(128) void fused_kernel(
    const float* __restrict__ M, const float* __restrict__ Wq,
    const float* __restrict__ Wc, const float* __restrict__ bc,
    const float* __restrict__ lnAg, const float* __restrict__ lnAb,
    const float* __restrict__ W1, const float* __restrict__ b1,
    const float* __restrict__ W2t, const float* __restrict__ b2,
    const float* __restrict__ lnBg, const float* __restrict__ lnBb,
    float* __restrict__ hbuf,
    const float* __restrict__ f1w, const float* __restrict__ f1b,
    const float* __restrict__ f2w, const float* __restrict__ f2b,
    const float* __restrict__ f3w, const float* __restrict__ f3b,
    const float* __restrict__ f4w, const float* __restrict__ f4b,
    float* __restrict__ out) {
  __shared__ __align__(16) float4 so4[16][7];
  __shared__ __align__(16) float stv[16 * 20];
  __shared__ __align__(16) float sc[128 * 20];

  int tid = threadIdx.x;
  int b = blockIdx.y;
  int p16 = tid & 15;
  int part = tid >> 4;
  int l = blockIdx.x * 16 + p16;
  bool act = l < L_;
  int lc = act ? l : L_ - 1;
  int pos = b * L_ + lc;

  float hv[E_];
#pragma unroll
  for (int e4 = 0; e4 < 5; e4++) {
    float4 h4 = *(const float4*)(hbuf + pos * E_ + e4 * 4);
    hv[e4 * 4 + 0] = h4.x; hv[e4 * 4 + 1] = h4.y;
    hv[e4 * 4 + 2] = h4.z; hv[e4 * 4 + 3] = h4.w;
  }

  if (part < H_) {
    float4 qsrc = *(const float4*)(hbuf + pos * E_ + part * 4);
    float q[4];
#pragma unroll
    for (int d = 0; d < 4; d++) {
      q[d] = (Wq[d * 4 + 0] * qsrc.x + Wq[d * 4 + 1] * qsrc.y +
              Wq[d * 4 + 2] * qsrc.z + Wq[d * 4 + 3] * qsrc.w) *
             SCALE;
    }
    float mq[36];
    mono36(q, mq);
    qcoef(mq);
    const float* Mb = M + (b * H_ + part) * MST2;
    float oc[5];
#pragma unroll
    for (int c = 0; c < 5; c++) {
      const float4* Mr = (const float4*)(Mb + c * 36);
      float a0 = 0.f, a1 = 0.f, a2 = 0.f, a3 = 0.f;
#pragma unroll
      for (int g = 0; g < 9; g++) {
        float4 w4 = Mr[g];
        a0 += w4.x * mq[g * 4 + 0];
        a1 += w4.y * mq[g * 4 + 1];
        a2 += w4.z * mq[g * 4 + 2];
        a3 += w4.w * mq[g * 4 + 3];
      }
      oc[c] = (a0 + a1) + (a2 + a3);
    }
    float inv = 1.f / oc[4];
    so4[p16][part] =
        make_float4(oc[0] * inv, oc[1] * inv, oc[2] * inv, oc[3] * inv);
  }
  __syncthreads();

  float o[E_];
#pragma unroll
  for (int hh = 0; hh < H_; hh++) {
    float4 o4 = so4[p16][hh];
    o[hh * 4 + 0] = o4.x; o[hh * 4 + 1] = o4.y;
    o[hh * 4 + 2] = o4.z; o[hh * 4 + 3] = o4.w;
  }
  int r0 = (part < 4) ? part * 3 : 12 + (part - 4) * 2;
  int nr = (part < 4) ? 3 : 2;
  for (int r = 0; r < nr; r++) {
    int row = r0 + r;
    float acc = bc[row];
    DOT20G(acc, Wc, row, o);
    stv[p16 * 20 + row] = acc;
  }
  __syncthreads();

  float tv[E_];
#pragma unroll
  for (int e4 = 0; e4 < 5; e4++) {
    float4 t4 = *(const float4*)(stv + p16 * 20 + e4 * 4);
    tv[e4 * 4 + 0] = t4.x + hv[e4 * 4 + 0];
    tv[e4 * 4 + 1] = t4.y + hv[e4 * 4 + 1];
    tv[e4 * 4 + 2] = t4.z + hv[e4 * 4 + 2];
    tv[e4 * 4 + 3] = t4.w + hv[e4 * 4 + 3];
  }
  float mu = 0.f;
#pragma unroll
  for (int e = 0; e < E_; e++) mu += tv[e];
  mu *= (1.f / E_);
  float var = 0.f;
#pragma unroll
  for (int e = 0; e < E_; e++) { float d = tv[e] - mu; var += d * d; }
  var *= (1.f / E_);
  float rs = rsqrtf(var + 1e-5f);
  float h1[E_];
#pragma unroll
  for (int e = 0; e < E_; e++) h1[e] = (tv[e] - mu) * rs * lnAg[e] + lnAb[e];

  float g2p[E_];
#pragma unroll
  for (int e = 0; e < E_; e++) g2p[e] = 0.f;
  int jf0 = part * (FF_ / 8);
#pragma unroll
  for (int jj = 0; jj < FF_ / 8; jj++) {
    int j = jf0 + jj;
    float f = b1[j];
    DOT20G(f, W1, j, h1);
    f = fmaxf(f, 0.f);
    const float4* Wr = (const float4*)(W2t + j * 20);
#pragma unroll
    for (int g = 0; g < 5; g++) {
      float4 w4 = Wr[g];
      g2p[g * 4 + 0] += w4.x * f;
      g2p[g * 4 + 1] += w4.y * f;
      g2p[g * 4 + 2] += w4.z * f;
      g2p[g * 4 + 3] += w4.w * f;
    }
  }
  float4* scw = (float4*)(sc + tid * 20);
#pragma unroll
  for (int g = 0; g < 5; g++)
    scw[g] = make_float4(g2p[g * 4], g2p[g * 4 + 1], g2p[g * 4 + 2],
                         g2p[g * 4 + 3]);
  __syncthreads();

  float g2[E_];
#pragma unroll
  for (int e = 0; e < E_; e++) g2[e] = b2[e] + h1[e];
#pragma unroll
  for (int pp = 0; pp < 8; pp++) {
    const float4* r = (const float4*)(sc + (pp * 16 + p16) * 20);
#pragma unroll
    for (int g = 0; g < 5; g++) {
      float4 v4 = r[g];
      g2[g * 4 + 0] += v4.x; g2[g * 4 + 1] += v4.y;
      g2[g * 4 + 2] += v4.z; g2[g * 4 + 3] += v4.w;
    }
  }
  float mu2 = 0.f;
#pragma unroll
  for (int e = 0; e < E_; e++) mu2 += g2[e];
  mu2 *= (1.f / E_);
  float var2 = 0.f;
#pragma unroll
  for (int e = 0; e < E_; e++) { float d = g2[e] - mu2; var2 += d * d; }
  var2 *= (1.f / E_);
  float rs2 = rsqrtf(var2 + 1e-5f);
  float hn[E_];
#pragma unroll
  for (int e = 0; e < E_; e++) hn[e] = (g2[e] - mu2) * rs2 * lnBg[e] + lnBb[e];

  if (!LAST) {
    if (act && part == 0) {
#pragma unroll
      for (int e4 = 0; e4 < 5; e4++) {
        *(float4*)(hbuf + pos * E_ + e4 * 4) =
            make_float4(hn[e4 * 4], hn[e4 * 4 + 1], hn[e4 * 4 + 2],
                        hn[e4 * 4 + 3]);
      }
    }
  } else {
    __syncthreads();
#pragma unroll
    for (int j = 0; j < DEC_ / 8; j++) {
      int jj = part * (DEC_ / 8) + j;
      float a = f1b[jj];
      DOT20G(a, f1w, jj, hn);
      sc[p16 * 101 + jj] = fmaxf(a, 0.f);
    }
    __syncthreads();
    float d1[DEC_];
#pragma unroll
    for (int k = 0; k < DEC_; k++) d1[k] = sc[p16 * 101 + k];
#pragma unroll
    for (int j = 0; j < DEC_ / 8; j++) {
      int jj = part * (DEC_ / 8) + j;
      float a = f2b[jj];
      DOT40G(a, f2w, jj, d1);
      sc[p16 * 101 + 40 + jj] = fmaxf(a, 0.f);
    }
    __syncthreads();
    float d2[DEC_];
#pragma unroll
    for (int k = 0; k < DEC_; k++) d2[k] = sc[p16 * 101 + 40 + k];
    if (part < 5) {
#pragma unroll
      for (int j = 0; j < 4; j++) {
        int ee = part * 4 + j;
        float a = f3b[ee];
        DOT40G(a, f3w, ee, d2);
        sc[p16 * 101 + 80 + ee] = fmaxf(a, 0.f);
      }
    }
    __syncthreads();
    if (act && part == 0) {
      float z = f4b[0];
      const float* dv = sc + p16 * 101 + 80;
      DOT20G(z, f4w, 0, dv);
      out[pos] = 1.f / (1.f + __expf(-z));
    }
  }
}

// ---------------------------------------------------------------------------
extern "C" void kernel_launch(void* const* d_in, const int* in_sizes, int n_in,
                              void* d_out, int out_size, void* d_ws,
                              size_t ws_size, hipStream_t stream) {
  const float* x    = (const float*)d_in[0];
  const float* cw   = (const float*)d_in[1];
  const float* Wv   = (const float*)d_in[2];
  const float* Wk   = (const float*)d_in[3];
  const float* Wq   = (const float*)d_in[4];
  const float* Wc   = (const float*)d_in[5];
  const float* bc   = (const float*)d_in[6];
  const float* lnAg = (const float*)d_in[7];
  const float* lnAb = (const float*)d_in[8];
  const float* W1   = (const float*)d_in[9];
  const float* b1   = (const float*)d_in[10];
  const float* W2   = (const float*)d_in[11];
  const float* b2   = (const float*)d_in[12];
  const float* lnBg = (const float*)d_in[13];
  const float* lnBb = (const float*)d_in[14];
  const float* f1w  = (const float*)d_in[15];
  const float* f1b  = (const float*)d_in[16];
  const float* f2w  = (const float*)d_in[17];
  const float* f2b  = (const float*)d_in[18];
  const float* f3w  = (const float*)d_in[19];
  const float* f3b  = (const float*)d_in[20];
  const float* f4w  = (const float*)d_in[21];
  const float* f4b  = (const float*)d_in[22];
  float* out = (float*)d_out;

  // ws floats: h 200000 | Mall 4*1800 | W2t 4*2400
  float* ws = (float*)d_ws;
  float* h = ws;
  float* Mall = ws + 200000;
  float* W2t = Mall + 4 * MLAYER;

  void* args[] = {
      (void*)&x,    (void*)&cw,   (void*)&Wv,   (void*)&Wk,   (void*)&Wq,
      (void*)&Wc,   (void*)&bc,   (void*)&lnAg, (void*)&lnAb, (void*)&W1,
      (void*)&b1,   (void*)&W2,   (void*)&b2,   (void*)&lnBg, (void*)&lnBb,
      (void*)&f1w,  (void*)&f1b,  (void*)&f2w,  (void*)&f2b,  (void*)&f3w,
      (void*)&f3b,  (void*)&f4w,  (void*)&f4b,  (void*)&out,  (void*)&h,
      (void*)&Mall, (void*)&W2t};

  hipError_t err = hipLaunchCooperativeKernel(
      megakernel, dim3(GRID_), dim3(BLK_), args, 0u, stream);

  if (err != hipSuccess) {
    // Fallback: original verified 9-kernel pipeline.
    conv_pe_kernel<<<(B_ * L_ * E_ + 255) / 256, 256, 0, stream>>>(x, cw, h,
                                                                   Mall);
    for (int i = 0; i < 4; i++) {
      moment_kernel<<<B_ * H_ * NCH, 192, 0, stream>>>(
          h, Wk + i * 16, Wv + i * 16, W2 + i * 2400, W2t, Mall + i * MLAYER);
      dim3 grid((L_ + 15) / 16, B_);
      if (i < 3) {
        fused_kernel<0><<<grid, 128, 0, stream>>>(
            Mall + i * MLAYER, Wq + i * 16, Wc + i * 400, bc + i * 20,
            lnAg + i * 20, lnAb + i * 20, W1 + i * 2400, b1 + i * 120, W2t,
            b2 + i * 20, lnBg + i * 20, lnBb + i * 20, h, f1w, f1b, f2w, f2b,
            f3w, f3b, f4w, f4b, out);
      } else {
        fused_kernel<1><<<grid, 128, 0, stream>>>(
            Mall + i * MLAYER, Wq + i * 16, Wc + i * 400, bc + i * 20,
            lnAg + i * 20, lnAb + i * 20, W1 + i * 2400, b1 + i * 120, W2t,
            b2 + i * 20, lnBg + i * 20, lnBb + i * 20, h, f1w, f1b, f2w, f2b,
            f3w, f3b, f4w, f4b, out);
      }
    }
  }
}

// Round 2
// 347.116 us; speedup vs baseline: 1.1103x; 1.1103x over previous
//
#include <hip/hip_runtime.h>
#include <math.h>

#define B_ 2
#define L_ 5000
#define E_ 20
#define H_ 5
#define FF_ 120
#define DEC_ 40
#define K_ 50
#define PAD_ 25
#define SCALE 0.22360679774997896f  // 1/sqrt(E)

#define NM 35                    // symmetric monomials deg<=3 in 4 vars
#define MST2 180                 // per-(b,h): 5 c-slots x 36 (35 used + pad)
#define MLAYER (B_ * H_ * MST2)  // 1800 floats per layer

// ---- persistent-kernel geometry ----
#define BLK_ 512                 // 64 positions x 8 parts; part is wave-uniform
#define NPOS 64
#define TPB_ 79                  // ceil(L/64) tiles per batch
#define GRID_ (B_ * TPB_)        // 158 blocks; 1 block/CU guaranteed resident
#define MCH 512                  // keys per moment chunk
#define NCHU 10                  // ceil(L/512); 2*5*10 = 100 units <= 158 blocks

typedef float v2f __attribute__((ext_vector_type(2)));
__device__ __forceinline__ v2f vsplat(float x) { v2f r; r.x = x; r.y = x; return r; }

// monomial index tables; slot 4 is the constant-1 slot.
__constant__ int TD[NM] = {4, 0,1,2,3, 0,0,0,0,1,1,1,2,2,3,
                           0,0,0,0,0,0,0,0,0,0,1,1,1,1,1,1,2,2,2,3};
__constant__ int TE[NM] = {4, 4,4,4,4, 0,1,2,3,1,2,3,2,3,3,
                           0,0,0,0,1,1,1,2,2,3,1,1,1,2,2,3,2,2,3,3};
__constant__ int TF[NM] = {4, 4,4,4,4, 4,4,4,4,4,4,4,4,4,4,
                           0,1,2,3,1,2,3,2,3,3,1,2,3,2,3,3,2,3,3,3};

__device__ __forceinline__ void mono36(const float x[4], float m[36]) {
  int idx = 0;
  m[idx++] = 1.f;
#pragma unroll
  for (int d = 0; d < 4; d++) m[idx++] = x[d];
#pragma unroll
  for (int d = 0; d < 4; d++)
#pragma unroll
    for (int e = d; e < 4; e++) m[idx++] = x[d] * x[e];
#pragma unroll
  for (int d = 0; d < 4; d++)
#pragma unroll
    for (int e = d; e < 4; e++)
#pragma unroll
      for (int f = e; f < 4; f++) m[idx++] = x[d] * x[e] * x[f];
  m[35] = 0.f;
}

__device__ __forceinline__ void qcoef(float* mq) {
  const float S = 1.f / 6.f;
  mq[5]  *= 0.5f; mq[9]  *= 0.5f; mq[12] *= 0.5f; mq[14] *= 0.5f;
  mq[15] *= S;    mq[25] *= S;    mq[31] *= S;    mq[34] *= S;
  mq[16] *= 0.5f; mq[17] *= 0.5f; mq[18] *= 0.5f; mq[19] *= 0.5f;
  mq[22] *= 0.5f; mq[24] *= 0.5f; mq[26] *= 0.5f; mq[27] *= 0.5f;
  mq[28] *= 0.5f; mq[30] *= 0.5f; mq[32] *= 0.5f; mq[33] *= 0.5f;
}

#define DOT20G(res, W, row, vec)                                     \
  {                                                                  \
    const float4* Wr = (const float4*)((W) + (row) * 20);            \
    float c0 = 0.f, c1 = 0.f, c2 = 0.f, c3 = 0.f;                    \
    _Pragma("unroll") for (int g5 = 0; g5 < 5; g5++) {               \
      float4 w4 = Wr[g5];                                            \
      c0 += w4.x * vec[g5 * 4 + 0];                                  \
      c1 += w4.y * vec[g5 * 4 + 1];                                  \
      c2 += w4.z * vec[g5 * 4 + 2];                                  \
      c3 += w4.w * vec[g5 * 4 + 3];                                  \
    }                                                                \
    res += (c0 + c1) + (c2 + c3);                                    \
  }

#define DOT40G(res, W, row, vec)                                     \
  {                                                                  \
    const float4* Wr = (const float4*)((W) + (row) * 40);            \
    float c0 = 0.f, c1 = 0.f, c2 = 0.f, c3 = 0.f;                    \
    _Pragma("unroll") for (int g5 = 0; g5 < 10; g5++) {              \
      float4 w4 = Wr[g5];                                            \
      c0 += w4.x * vec[g5 * 4 + 0];                                  \
      c1 += w4.y * vec[g5 * 4 + 1];                                  \
      c2 += w4.z * vec[g5 * 4 + 2];                                  \
      c3 += w4.w * vec[g5 * 4 + 3];                                  \
    }                                                                \
    res += (c0 + c1) + (c2 + c3);                                    \
  }

// LDS: union of moment-phase staging and fused-phase hand-off buffers.
struct SUf {
  float4 so4[NPOS][7];   // [p][head], padded
  float stv[NPOS * E_];  // [p][20]
  float sc[BLK_ * E_];   // [tid][20]; decoder reuses as p*101
};
union __align__(16) SU {
  float kvs[10][MCH + 2];  // 20.6 KB
  SUf f;                   // 53.2 KB
};

// ---------------------------------------------------------------------------
// Hand-rolled grid barrier. State lives in __device__ globals (zero-init at
// module load; the workspace is poison-filled by the harness so it cannot
// hold barrier state). Sense-free design: cnt returns to 0 after every
// barrier (last arriver resets it BEFORE bumping gen, with release order),
// gen increments monotonically -> works across bench iterations and rocprof
// replays without reinitialization. Leader-only protocol, same fences as
// cg::grid_group::sync (release wb before arrive, acquire inv on exit).
// ---------------------------------------------------------------------------
__device__ unsigned g_cnt;
__device__ unsigned g_gen;

__device__ __forceinline__ void grid_barrier() {
  __syncthreads();  // each wave drains its own vmcnt before s_barrier
  if (threadIdx.x == 0) {
    __threadfence();  // release: make this block's global writes visible
    unsigned g = __hip_atomic_load(&g_gen, __ATOMIC_RELAXED,
                                   __HIP_MEMORY_SCOPE_AGENT);
    unsigned arr = __hip_atomic_fetch_add(&g_cnt, 1u, __ATOMIC_ACQ_REL,
                                          __HIP_MEMORY_SCOPE_AGENT);
    if (arr == GRID_ - 1) {
      __hip_atomic_store(&g_cnt, 0u, __ATOMIC_RELAXED,
                         __HIP_MEMORY_SCOPE_AGENT);
      __hip_atomic_fetch_add(&g_gen, 1u, __ATOMIC_ACQ_REL,
                             __HIP_MEMORY_SCOPE_AGENT);
    } else {
      while (__hip_atomic_load(&g_gen, __ATOMIC_ACQUIRE,
                               __HIP_MEMORY_SCOPE_AGENT) == g) {
        __builtin_amdgcn_s_sleep(2);
      }
    }
  }
  __syncthreads();  // leader's acquire-inv precedes other waves' loads
}

// ---------------------------------------------------------------------------
// Fused layer phase (verbatim math from the proven fused_kernel; 64 pos x
// 8 parts; part = tid>>6 is wave-uniform).
// ---------------------------------------------------------------------------
__device__ __forceinline__ void fused_phase(
    bool last, int tid, int p, int part, int fb, int pos, bool act,
    const float* __restrict__ M, const float* __restrict__ Wq,
    const float* __restrict__ Wc, const float* __restrict__ bc,
    const float* __restrict__ lnAg, const float* __restrict__ lnAb,
    const float* __restrict__ W1, const float* __restrict__ b1,
    const float* __restrict__ W2t, const float* __restrict__ b2,
    const float* __restrict__ lnBg, const float* __restrict__ lnBb,
    float* __restrict__ hbuf,
    const float* __restrict__ f1w, const float* __restrict__ f1b,
    const float* __restrict__ f2w, const float* __restrict__ f2b,
    const float* __restrict__ f3w, const float* __restrict__ f3b,
    const float* __restrict__ f4w, const float* __restrict__ f4b,
    float* __restrict__ out, SUf* F) {
  // residual vector (constant-indexed only -> stays in VGPRs)
  float hv[E_];
#pragma unroll
  for (int e4 = 0; e4 < 5; e4++) {
    float4 h4 = *(const float4*)(hbuf + pos * E_ + e4 * 4);
    hv[e4 * 4 + 0] = h4.x; hv[e4 * 4 + 1] = h4.y;
    hv[e4 * 4 + 2] = h4.z; hv[e4 * 4 + 3] = h4.w;
  }

  // ---- A: attention eval, head = part (parts 5-7 idle) ----
  if (part < H_) {
    float4 qsrc = *(const float4*)(hbuf + pos * E_ + part * 4);
    float q[4];
#pragma unroll
    for (int d = 0; d < 4; d++) {
      q[d] = (Wq[d * 4 + 0] * qsrc.x + Wq[d * 4 + 1] * qsrc.y +
              Wq[d * 4 + 2] * qsrc.z + Wq[d * 4 + 3] * qsrc.w) *
             SCALE;
    }
    float mq[36];
    mono36(q, mq);
    qcoef(mq);
    const float* Mb = M + (fb * H_ + part) * MST2;
    float oc[5];
#pragma unroll
    for (int c = 0; c < 5; c++) {
      const float4* Mr = (const float4*)(Mb + c * 36);
      float a0 = 0.f, a1 = 0.f, a2 = 0.f, a3 = 0.f;
#pragma unroll
      for (int g = 0; g < 9; g++) {
        float4 w4 = Mr[g];
        a0 += w4.x * mq[g * 4 + 0];
        a1 += w4.y * mq[g * 4 + 1];
        a2 += w4.z * mq[g * 4 + 2];
        a3 += w4.w * mq[g * 4 + 3];
      }
      oc[c] = (a0 + a1) + (a2 + a3);
    }
    float inv = 1.f / oc[4];
    F->so4[p][part] =
        make_float4(oc[0] * inv, oc[1] * inv, oc[2] * inv, oc[3] * inv);
  }
  __syncthreads();

  // ---- B: Wc rows per part + bias -> stv ----
  float o[E_];
#pragma unroll
  for (int hh = 0; hh < H_; hh++) {
    float4 o4 = F->so4[p][hh];
    o[hh * 4 + 0] = o4.x; o[hh * 4 + 1] = o4.y;
    o[hh * 4 + 2] = o4.z; o[hh * 4 + 3] = o4.w;
  }
  int r0 = (part < 4) ? part * 3 : 12 + (part - 4) * 2;
  int nr = (part < 4) ? 3 : 2;
  for (int r = 0; r < nr; r++) {
    int row = r0 + r;
    float acc = bc[row];
    DOT20G(acc, Wc, row, o);
    F->stv[p * E_ + row] = acc;
  }
  __syncthreads();

  // ---- C: add residual, LN_A (redundant per thread) ----
  float tv[E_];
#pragma unroll
  for (int e4 = 0; e4 < 5; e4++) {
    float4 t4 = *(const float4*)(F->stv + p * E_ + e4 * 4);
    tv[e4 * 4 + 0] = t4.x + hv[e4 * 4 + 0];
    tv[e4 * 4 + 1] = t4.y + hv[e4 * 4 + 1];
    tv[e4 * 4 + 2] = t4.z + hv[e4 * 4 + 2];
    tv[e4 * 4 + 3] = t4.w + hv[e4 * 4 + 3];
  }
  float mu = 0.f;
#pragma unroll
  for (int e = 0; e < E_; e++) mu += tv[e];
  mu *= (1.f / E_);
  float var = 0.f;
#pragma unroll
  for (int e = 0; e < E_; e++) { float d = tv[e] - mu; var += d * d; }
  var *= (1.f / E_);
  float rs = rsqrtf(var + 1e-5f);
  float h1[E_];
#pragma unroll
  for (int e = 0; e < E_; e++) h1[e] = (tv[e] - mu) * rs * lnAg[e] + lnAb[e];

  // ---- D: FFN, 15 rows per part ----
  float g2p[E_];
#pragma unroll
  for (int e = 0; e < E_; e++) g2p[e] = 0.f;
  int jf0 = part * (FF_ / 8);
#pragma unroll
  for (int jj = 0; jj < FF_ / 8; jj++) {
    int j = jf0 + jj;
    float f = b1[j];
    DOT20G(f, W1, j, h1);
    f = fmaxf(f, 0.f);
    const float4* Wr = (const float4*)(W2t + j * 20);
#pragma unroll
    for (int g = 0; g < 5; g++) {
      float4 w4 = Wr[g];
      g2p[g * 4 + 0] += w4.x * f;
      g2p[g * 4 + 1] += w4.y * f;
      g2p[g * 4 + 2] += w4.z * f;
      g2p[g * 4 + 3] += w4.w * f;
    }
  }
  float4* scw = (float4*)(F->sc + tid * E_);
#pragma unroll
  for (int g = 0; g < 5; g++)
    scw[g] = make_float4(g2p[g * 4], g2p[g * 4 + 1], g2p[g * 4 + 2],
                         g2p[g * 4 + 3]);
  __syncthreads();

  // ---- E: reduce 8 partials + b2 + residual(h1), LN_B ----
  float g2[E_];
#pragma unroll
  for (int e = 0; e < E_; e++) g2[e] = b2[e] + h1[e];
#pragma unroll
  for (int pp = 0; pp < 8; pp++) {
    const float4* r = (const float4*)(F->sc + (pp * NPOS + p) * E_);
#pragma unroll
    for (int g = 0; g < 5; g++) {
      float4 v4 = r[g];
      g2[g * 4 + 0] += v4.x; g2[g * 4 + 1] += v4.y;
      g2[g * 4 + 2] += v4.z; g2[g * 4 + 3] += v4.w;
    }
  }
  float mu2 = 0.f;
#pragma unroll
  for (int e = 0; e < E_; e++) mu2 += g2[e];
  mu2 *= (1.f / E_);
  float var2 = 0.f;
#pragma unroll
  for (int e = 0; e < E_; e++) { float d = g2[e] - mu2; var2 += d * d; }
  var2 *= (1.f / E_);
  float rs2 = rsqrtf(var2 + 1e-5f);
  float hn[E_];
#pragma unroll
  for (int e = 0; e < E_; e++) hn[e] = (g2[e] - mu2) * rs2 * lnBg[e] + lnBb[e];

  if (!last) {
    if (act && part == 0) {
#pragma unroll
      for (int e4 = 0; e4 < 5; e4++) {
        *(float4*)(hbuf + pos * E_ + e4 * 4) =
            make_float4(hn[e4 * 4], hn[e4 * 4 + 1], hn[e4 * 4 + 2],
                        hn[e4 * 4 + 3]);
      }
    }
  } else {
    __syncthreads();  // reduce reads done before reusing sc
#pragma unroll
    for (int j = 0; j < DEC_ / 8; j++) {
      int jj = part * (DEC_ / 8) + j;
      float a = f1b[jj];
      DOT20G(a, f1w, jj, hn);
      F->sc[p * 101 + jj] = fmaxf(a, 0.f);
    }
    __syncthreads();
    float d1[DEC_];
#pragma unroll
    for (int k = 0; k < DEC_; k++) d1[k] = F->sc[p * 101 + k];
#pragma unroll
    for (int j = 0; j < DEC_ / 8; j++) {
      int jj = part * (DEC_ / 8) + j;
      float a = f2b[jj];
      DOT40G(a, f2w, jj, d1);
      F->sc[p * 101 + 40 + jj] = fmaxf(a, 0.f);
    }
    __syncthreads();
    float d2[DEC_];
#pragma unroll
    for (int k = 0; k < DEC_; k++) d2[k] = F->sc[p * 101 + 40 + k];
    if (part < 5) {
#pragma unroll
      for (int j = 0; j < 4; j++) {
        int ee = part * 4 + j;
        float a = f3b[ee];
        DOT40G(a, f3w, ee, d2);
        F->sc[p * 101 + 80 + ee] = fmaxf(a, 0.f);
      }
    }
    __syncthreads();
    if (act && part == 0) {
      float z = f4b[0];
      const float* dv = F->sc + p * 101 + 80;
      DOT20G(z, f4w, 0, dv);
      out[pos] = 1.f / (1.f + __expf(-z));
    }
  }
}

// ---------------------------------------------------------------------------
// Persistent megakernel: conv+PE -> 4 x (moments -> fused layer), barrier-
// synced. Ordinary launch; 158 blocks x 512 threads; __launch_bounds__(512,2)
// caps VGPR<=256 so 1 block/CU is guaranteed resource-wise -> all 158 blocks
// co-resident on 256 CUs (no deadlock possible).
// ---------------------------------------------------------------------------
__global__ __launch_bounds__(BLK_, 2) void megakernel(
    const float* __restrict__ x, const float* __restrict__ cw,
    const float* __restrict__ Wv, const float* __restrict__ Wk,
    const float* __restrict__ Wq, const float* __restrict__ Wc,
    const float* __restrict__ bc, const float* __restrict__ lnAg,
    const float* __restrict__ lnAb, const float* __restrict__ W1,
    const float* __restrict__ b1, const float* __restrict__ W2,
    const float* __restrict__ b2, const float* __restrict__ lnBg,
    const float* __restrict__ lnBb,
    const float* __restrict__ f1w, const float* __restrict__ f1b,
    const float* __restrict__ f2w, const float* __restrict__ f2b,
    const float* __restrict__ f3w, const float* __restrict__ f3b,
    const float* __restrict__ f4w, const float* __restrict__ f4b,
    float* __restrict__ out, float* __restrict__ hbuf,
    float* __restrict__ Mall, float* __restrict__ W2t) {
  __shared__ SU S;
  const int tid = threadIdx.x;
  const int bid = blockIdx.x;

  // ---- phase 0: zero all M, transpose W2 (all layers), conv embed + PE.
  // PE depends only on (l,e): compute once, write both batches' conv+pe. ----
  {
    const int stride = GRID_ * BLK_;
    int tg = bid * BLK_ + tid;
    if (tg < 4 * MLAYER) Mall[tg] = 0.f;
    if (tg < 4 * E_ * FF_) {
      int i = tg / (E_ * FF_), r = tg % (E_ * FF_);
      int e = r / FF_, j = r % FF_;
      W2t[i * 2400 + j * E_ + e] = W2[i * 2400 + e * FF_ + j];
    }
    for (int idx = tg; idx < L_ * E_; idx += stride) {
      int e = idx % E_;
      int l = idx / E_;
      const float* xr0 = x;        // batch 0
      const float* xr1 = x + L_;   // batch 1
      const float* wr = cw + e * K_;
      float a0 = 0.f, a1 = 0.f, c0 = 0.f, c1 = 0.f;
#pragma unroll
      for (int k = 0; k < K_; k += 2) {
        int i0 = l + k - PAD_, i1 = i0 + 1;
        bool v0 = (i0 >= 0 && i0 < L_), v1 = (i1 >= 0 && i1 < L_);
        float w0 = wr[k], w1 = wr[k + 1];
        float x00 = v0 ? xr0[i0] : 0.f;
        float x01 = v1 ? xr0[i1] : 0.f;
        float x10 = v0 ? xr1[i0] : 0.f;
        float x11 = v1 ? xr1[i1] : 0.f;
        a0 += x00 * w0;
        a1 += x01 * w1;
        c0 += x10 * w0;
        c1 += x11 * w1;
      }
      double expo =
          (e & 1) ? (double)(e + 1) / (double)E_ : (double)e / (double)E_;
      double factor = pow(10000.0, -expo);
      double arg = (double)l * factor;
      float pe = (e & 1) ? (float)cos(arg) : (float)sin(arg);
      hbuf[l * E_ + e] = (a0 + a1) + pe;
      hbuf[(L_ + l) * E_ + e] = (c0 + c1) + pe;
    }
  }
  grid_barrier();

  const int p = tid & (NPOS - 1);
  const int part = tid >> 6;  // wave-uniform
  const int fb = bid / TPB_;
  const int l = (bid % TPB_) * NPOS + p;
  const bool act = l < L_;
  const int lc = act ? l : L_ - 1;
  const int pos = fb * L_ + lc;

  for (int layer = 0; layer < 4; layer++) {
    // ---- moment phase: 100 units of (bh, 512-key chunk) ----
    if (bid < B_ * H_ * NCHU) {
      int bh = bid / NCHU, chunk = bid % NCHU;
      int mb = bh / H_, hh = bh % H_;
      const float* WkL = Wk + layer * 16;
      const float* WvL = Wv + layer * 16;
      {
        float wk[16], wv[16];
#pragma unroll
        for (int i2 = 0; i2 < 16; i2++) { wk[i2] = WkL[i2]; wv[i2] = WvL[i2]; }
        int j = chunk * MCH + tid;
        bool valid = j < L_;
        int jc = valid ? j : L_ - 1;
        float4 s4 = *(const float4*)(hbuf + (mb * L_ + jc) * E_ + hh * 4);
        float vm = valid ? 1.f : 0.f;
        int t = tid;
        S.kvs[0][t] = wk[0] * s4.x + wk[1] * s4.y + wk[2] * s4.z + wk[3] * s4.w;
        S.kvs[1][t] = wk[4] * s4.x + wk[5] * s4.y + wk[6] * s4.z + wk[7] * s4.w;
        S.kvs[2][t] = wk[8] * s4.x + wk[9] * s4.y + wk[10] * s4.z + wk[11] * s4.w;
        S.kvs[3][t] = wk[12] * s4.x + wk[13] * s4.y + wk[14] * s4.z + wk[15] * s4.w;
        S.kvs[4][t] = 1.f;
        S.kvs[5][t] = (wv[0] * s4.x + wv[1] * s4.y + wv[2] * s4.z + wv[3] * s4.w) * vm;
        S.kvs[6][t] = (wv[4] * s4.x + wv[5] * s4.y + wv[6] * s4.z + wv[7] * s4.w) * vm;
        S.kvs[7][t] = (wv[8] * s4.x + wv[9] * s4.y + wv[10] * s4.z + wv[11] * s4.w) * vm;
        S.kvs[8][t] = (wv[12] * s4.x + wv[13] * s4.y + wv[14] * s4.z + wv[15] * s4.w) * vm;
        S.kvs[9][t] = vm;
      }
      __syncthreads();
      if (tid < 2 * NM * 5) {  // 350 threads: (m,c) x half-range
        int t = tid % (NM * 5);
        int half = tid / (NM * 5);
        int m = t / 5, c = t % 5;
        int sd = TD[m], se = TE[m], sf = TF[m], sv = 5 + c;
        int j0 = half * (MCH / 2);
        v2f acc = vsplat(0.f);
#pragma unroll 4
        for (int j = 0; j < MCH / 2; j += 2) {
          v2f a = *(const v2f*)&S.kvs[sd][j0 + j];
          v2f bq = *(const v2f*)&S.kvs[se][j0 + j];
          v2f cq = *(const v2f*)&S.kvs[sf][j0 + j];
          v2f vv = *(const v2f*)&S.kvs[sv][j0 + j];
          acc += a * bq * cq * vv;
        }
        atomicAdd(&Mall[layer * MLAYER + bh * MST2 + c * 36 + m],
                  acc.x + acc.y);
      }
    }
    grid_barrier();

    // ---- fused layer phase ----
    fused_phase(layer == 3, tid, p, part, fb, pos, act,
                Mall + layer * MLAYER, Wq + layer * 16, Wc + layer * 400,
                bc + layer * 20, lnAg + layer * 20, lnAb + layer * 20,
                W1 + layer * 2400, b1 + layer * 120, W2t + layer * 2400,
                b2 + layer * 20, lnBg + layer * 20, lnBb + layer * 20, hbuf,
                f1w, f1b, f2w, f2b, f3w, f3b, f4w, f4b, out, &S.f);
    if (layer < 3) grid_barrier();
  }
}

// ---------------------------------------------------------------------------
extern "C" void kernel_launch(void* const* d_in, const int* in_sizes, int n_in,
                              void* d_out, int out_size, void* d_ws,
                              size_t ws_size, hipStream_t stream) {
  const float* x    = (const float*)d_in[0];
  const float* cw   = (const float*)d_in[1];
  const float* Wv   = (const float*)d_in[2];
  const float* Wk   = (const float*)d_in[3];
  const float* Wq   = (const float*)d_in[4];
  const float* Wc   = (const float*)d_in[5];
  const float* bc   = (const float*)d_in[6];
  const float* lnAg = (const float*)d_in[7];
  const float* lnAb = (const float*)d_in[8];
  const float* W1   = (const float*)d_in[9];
  const float* b1   = (const float*)d_in[10];
  const float* W2   = (const float*)d_in[11];
  const float* b2   = (const float*)d_in[12];
  const float* lnBg = (const float*)d_in[13];
  const float* lnBb = (const float*)d_in[14];
  const float* f1w  = (const float*)d_in[15];
  const float* f1b  = (const float*)d_in[16];
  const float* f2w  = (const float*)d_in[17];
  const float* f2b  = (const float*)d_in[18];
  const float* f3w  = (const float*)d_in[19];
  const float* f3b  = (const float*)d_in[20];
  const float* f4w  = (const float*)d_in[21];
  const float* f4b  = (const float*)d_in[22];
  float* out = (float*)d_out;

  // ws floats: h 200000 | Mall 4*1800 | W2t 4*2400
  float* ws = (float*)d_ws;
  float* h = ws;
  float* Mall = ws + 200000;
  float* W2t = Mall + 4 * MLAYER;

  megakernel<<<dim3(GRID_), dim3(BLK_), 0, stream>>>(
      x, cw, Wv, Wk, Wq, Wc, bc, lnAg, lnAb, W1, b1, W2, b2, lnBg, lnBb,
      f1w, f1b, f2w, f2b, f3w, f3b, f4w, f4b, out, h, Mall, W2t);
}

// Round 3
// 260.649 us; speedup vs baseline: 1.4786x; 1.3317x over previous
//
#include <hip/hip_runtime.h>
#include <math.h>

#define B_ 2
#define L_ 5000
#define E_ 20
#define H_ 5
#define FF_ 120
#define DEC_ 40
#define K_ 50
#define PAD_ 25
#define SCALE 0.22360679774997896f  // 1/sqrt(E)

#define NM 35                     // symmetric monomials deg<=3 in 4 vars
#define MST2 180                  // per-(b,h): 5 c-slots x 36 (35 used + pad)
#define LSTRIDE 1824              // per-layer M stride, 128B multiple (line isolation)

// ---- persistent-kernel geometry ----
#define BLK_ 512                  // 64 positions x 8 parts; part = tid>>6 wave-uniform
#define NPOS 64
#define TPB_ 79                   // ceil(L/64) tiles per batch
#define GRID_ (B_ * TPB_)         // 158 blocks <= 256 CUs -> all co-resident

typedef float v2f __attribute__((ext_vector_type(2)));
__device__ __forceinline__ v2f vsplat(float x) { v2f r; r.x = x; r.y = x; return r; }

// monomial index tables; slot 4 is the constant-1 slot.
__constant__ int TD[NM] = {4, 0,1,2,3, 0,0,0,0,1,1,1,2,2,3,
                           0,0,0,0,0,0,0,0,0,0,1,1,1,1,1,1,2,2,2,3};
__constant__ int TE[NM] = {4, 4,4,4,4, 0,1,2,3,1,2,3,2,3,3,
                           0,0,0,0,1,1,1,2,2,3,1,1,1,2,2,3,2,2,3,3};
__constant__ int TF[NM] = {4, 4,4,4,4, 4,4,4,4,4,4,4,4,4,4,
                           0,1,2,3,1,2,3,2,3,3,1,2,3,2,3,3,2,3,3,3};

__device__ __forceinline__ void mono36(const float x[4], float m[36]) {
  int idx = 0;
  m[idx++] = 1.f;
#pragma unroll
  for (int d = 0; d < 4; d++) m[idx++] = x[d];
#pragma unroll
  for (int d = 0; d < 4; d++)
#pragma unroll
    for (int e = d; e < 4; e++) m[idx++] = x[d] * x[e];
#pragma unroll
  for (int d = 0; d < 4; d++)
#pragma unroll
    for (int e = d; e < 4; e++)
#pragma unroll
      for (int f = e; f < 4; f++) m[idx++] = x[d] * x[e] * x[f];
  m[35] = 0.f;
}

__device__ __forceinline__ void qcoef(float* mq) {
  const float S = 1.f / 6.f;
  mq[5]  *= 0.5f; mq[9]  *= 0.5f; mq[12] *= 0.5f; mq[14] *= 0.5f;
  mq[15] *= S;    mq[25] *= S;    mq[31] *= S;    mq[34] *= S;
  mq[16] *= 0.5f; mq[17] *= 0.5f; mq[18] *= 0.5f; mq[19] *= 0.5f;
  mq[22] *= 0.5f; mq[24] *= 0.5f; mq[26] *= 0.5f; mq[27] *= 0.5f;
  mq[28] *= 0.5f; mq[30] *= 0.5f; mq[32] *= 0.5f; mq[33] *= 0.5f;
}

#define DOT20G(res, W, row, vec)                                     \
  {                                                                  \
    const float4* Wr = (const float4*)((W) + (row) * 20);            \
    float c0 = 0.f, c1 = 0.f, c2 = 0.f, c3 = 0.f;                    \
    _Pragma("unroll") for (int g5 = 0; g5 < 5; g5++) {               \
      float4 w4 = Wr[g5];                                            \
      c0 += w4.x * vec[g5 * 4 + 0];                                  \
      c1 += w4.y * vec[g5 * 4 + 1];                                  \
      c2 += w4.z * vec[g5 * 4 + 2];                                  \
      c3 += w4.w * vec[g5 * 4 + 3];                                  \
    }                                                                \
    res += (c0 + c1) + (c2 + c3);                                    \
  }

#define DOT40G(res, W, row, vec)                                     \
  {                                                                  \
    const float4* Wr = (const float4*)((W) + (row) * 40);            \
    float c0 = 0.f, c1 = 0.f, c2 = 0.f, c3 = 0.f;                    \
    _Pragma("unroll") for (int g5 = 0; g5 < 10; g5++) {              \
      float4 w4 = Wr[g5];                                            \
      c0 += w4.x * vec[g5 * 4 + 0];                                  \
      c1 += w4.y * vec[g5 * 4 + 1];                                  \
      c2 += w4.z * vec[g5 * 4 + 2];                                  \
      c3 += w4.w * vec[g5 * 4 + 3];                                  \
    }                                                                \
    res += (c0 + c1) + (c2 + c3);                                    \
  }

// LDS: hand-off buffers + persistent h mirror + (sc | kk) overlay.
// so4 7.0KB + stv 5.0KB + sh 5.0KB + max(sc 40KB, kk 12.9KB) = 57.0KB < 64KB.
struct SUf {
  float4 so4[NPOS][7];    // [p][head], padded
  float stv[NPOS * E_];   // [p][20] Wc hand-off
  float sh[NPOS * E_];    // [p][20] persistent current-h mirror (for dyn idx)
  union {
    float sc[BLK_ * E_];  // FFN partials / decoder scratch
    float kk[5 * 10 * 66];// moment staging [head][slot][pos], pad 66
  } u;
};

// ---------------------------------------------------------------------------
// Grid barrier, coherence-light version.
// All cross-block data is written via cache-bypassing ops (atomicAdd /
// sc0sc1 atomic stores), so NO L2-writeback fence is needed on arrive
// (RELEASE fetch_add drains the leader's vmcnt; __syncthreads drains each
// wave's own). Polling uses RELAXED loads (coherence-point read, NO cache
// invalidate) -> O(1) invalidates per barrier instead of O(polls): one
// ACQUIRE load on exit. State in __device__ globals: cnt self-resets, gen
// monotonic -> replay/graph safe.
// ---------------------------------------------------------------------------
__device__ unsigned g_cnt = 0;
__device__ unsigned g_gen = 0;

__device__ __forceinline__ void grid_barrier() {
  __syncthreads();  // each wave drains its own vmcnt (atomics included)
  if (threadIdx.x == 0) {
    unsigned g = __hip_atomic_load(&g_gen, __ATOMIC_RELAXED,
                                   __HIP_MEMORY_SCOPE_AGENT);
    unsigned arr = __hip_atomic_fetch_add(&g_cnt, 1u, __ATOMIC_RELEASE,
                                          __HIP_MEMORY_SCOPE_AGENT);
    if (arr == GRID_ - 1) {
      __hip_atomic_store(&g_cnt, 0u, __ATOMIC_RELAXED,
                         __HIP_MEMORY_SCOPE_AGENT);
      __hip_atomic_fetch_add(&g_gen, 1u, __ATOMIC_RELEASE,
                             __HIP_MEMORY_SCOPE_AGENT);
    } else {
      while (__hip_atomic_load(&g_gen, __ATOMIC_RELAXED,
                               __HIP_MEMORY_SCOPE_AGENT) == g) {
        __builtin_amdgcn_s_sleep(8);
      }
    }
    // single acquire: invalidate stale L1/L2 lines (M written by others,
    // plus any poison left cached from the harness's ws fill)
    (void)__hip_atomic_load(&g_gen, __ATOMIC_ACQUIRE,
                            __HIP_MEMORY_SCOPE_AGENT);
  }
  __syncthreads();
}

// ---------------------------------------------------------------------------
// In-block moment production: this block's 64 keys -> atomicAdd into Mdst.
// Producer: thread (p, part=h) computes k/v of its own position from sh.
// Reducer: head-wave h (64 lanes) sums 175 (m,c) products over 64 keys.
// ---------------------------------------------------------------------------
__device__ __forceinline__ void produce_M(
    int p, int part, int fb, bool act,
    const float* __restrict__ WkL, const float* __restrict__ WvL,
    float* __restrict__ Mdst, SUf* F) {
  __syncthreads();  // sc readers + sh writer done before kk overlay
  float* kk = F->u.kk;
  if (part < H_) {
    float4 s4 = *(const float4*)(F->sh + p * E_ + part * 4);
    float vm = act ? 1.f : 0.f;
    float* base = kk + part * 660 + p;
#pragma unroll
    for (int d = 0; d < 4; d++)
      base[d * 66] = WkL[d * 4 + 0] * s4.x + WkL[d * 4 + 1] * s4.y +
                     WkL[d * 4 + 2] * s4.z + WkL[d * 4 + 3] * s4.w;
    base[4 * 66] = 1.f;
#pragma unroll
    for (int d = 0; d < 4; d++)
      base[(5 + d) * 66] = (WvL[d * 4 + 0] * s4.x + WvL[d * 4 + 1] * s4.y +
                            WvL[d * 4 + 2] * s4.z + WvL[d * 4 + 3] * s4.w) * vm;
    base[9 * 66] = vm;
  }
  __syncthreads();
  if (part < H_) {
    const float* kb = kk + part * 660;
#pragma unroll
    for (int r = 0; r < 3; r++) {
      int mc = p + r * 64;
      if (mc < NM * 5) {
        int m = mc / 5, c = mc - m * 5;
        int sd = TD[m] * 66, se = TE[m] * 66, sf = TF[m] * 66,
            sv = (5 + c) * 66;
        v2f acc = vsplat(0.f);
#pragma unroll 8
        for (int j = 0; j < NPOS; j += 2) {
          v2f a  = *(const v2f*)(kb + sd + j);
          v2f bq = *(const v2f*)(kb + se + j);
          v2f cq = *(const v2f*)(kb + sf + j);
          v2f vv = *(const v2f*)(kb + sv + j);
          acc += a * bq * cq * vv;
        }
        atomicAdd(&Mdst[(fb * H_ + part) * MST2 + c * 36 + m], acc.x + acc.y);
      }
    }
  }
}

// ---------------------------------------------------------------------------
// Fused layer (proven math; h kept in registers across layers).
// ---------------------------------------------------------------------------
__device__ __forceinline__ void fused_phase(
    bool last, int tid, int p, int part, int fb, int pos, bool act,
    const float* __restrict__ M, const float* __restrict__ Wq,
    const float* __restrict__ Wc, const float* __restrict__ bc,
    const float* __restrict__ lnAg, const float* __restrict__ lnAb,
    const float* __restrict__ W1, const float* __restrict__ b1,
    const float* __restrict__ W2t, const float* __restrict__ b2,
    const float* __restrict__ lnBg, const float* __restrict__ lnBb,
    const float* __restrict__ f1w, const float* __restrict__ f1b,
    const float* __restrict__ f2w, const float* __restrict__ f2b,
    const float* __restrict__ f3w, const float* __restrict__ f3b,
    const float* __restrict__ f4w, const float* __restrict__ f4b,
    float* __restrict__ out, float* hv /* [E_] in: h, out: new h */,
    SUf* F) {
  // ---- A: attention eval, head = part (parts 5-7 idle) ----
  if (part < H_) {
    float4 qsrc = *(const float4*)(F->sh + p * E_ + part * 4);  // dyn idx via LDS
    float q[4];
#pragma unroll
    for (int d = 0; d < 4; d++) {
      q[d] = (Wq[d * 4 + 0] * qsrc.x + Wq[d * 4 + 1] * qsrc.y +
              Wq[d * 4 + 2] * qsrc.z + Wq[d * 4 + 3] * qsrc.w) *
             SCALE;
    }
    float mq[36];
    mono36(q, mq);
    qcoef(mq);
    const float* Mb = M + (fb * H_ + part) * MST2;
    float oc[5];
#pragma unroll
    for (int c = 0; c < 5; c++) {
      const float4* Mr = (const float4*)(Mb + c * 36);
      float a0 = 0.f, a1 = 0.f, a2 = 0.f, a3 = 0.f;
#pragma unroll
      for (int g = 0; g < 9; g++) {
        float4 w4 = Mr[g];
        a0 += w4.x * mq[g * 4 + 0];
        a1 += w4.y * mq[g * 4 + 1];
        a2 += w4.z * mq[g * 4 + 2];
        a3 += w4.w * mq[g * 4 + 3];
      }
      oc[c] = (a0 + a1) + (a2 + a3);
    }
    float inv = 1.f / oc[4];
    F->so4[p][part] =
        make_float4(oc[0] * inv, oc[1] * inv, oc[2] * inv, oc[3] * inv);
  }
  __syncthreads();

  // ---- B: Wc rows per part + bias -> stv ----
  float o[E_];
#pragma unroll
  for (int hh = 0; hh < H_; hh++) {
    float4 o4 = F->so4[p][hh];
    o[hh * 4 + 0] = o4.x; o[hh * 4 + 1] = o4.y;
    o[hh * 4 + 2] = o4.z; o[hh * 4 + 3] = o4.w;
  }
  int r0 = (part < 4) ? part * 3 : 12 + (part - 4) * 2;
  int nr = (part < 4) ? 3 : 2;
  for (int r = 0; r < nr; r++) {
    int row = r0 + r;
    float acc = bc[row];
    DOT20G(acc, Wc, row, o);
    F->stv[p * E_ + row] = acc;
  }
  __syncthreads();

  // ---- C: add residual (hv regs), LN_A (redundant per thread) ----
  float tv[E_];
#pragma unroll
  for (int e4 = 0; e4 < 5; e4++) {
    float4 t4 = *(const float4*)(F->stv + p * E_ + e4 * 4);
    tv[e4 * 4 + 0] = t4.x + hv[e4 * 4 + 0];
    tv[e4 * 4 + 1] = t4.y + hv[e4 * 4 + 1];
    tv[e4 * 4 + 2] = t4.z + hv[e4 * 4 + 2];
    tv[e4 * 4 + 3] = t4.w + hv[e4 * 4 + 3];
  }
  float mu = 0.f;
#pragma unroll
  for (int e = 0; e < E_; e++) mu += tv[e];
  mu *= (1.f / E_);
  float var = 0.f;
#pragma unroll
  for (int e = 0; e < E_; e++) { float d = tv[e] - mu; var += d * d; }
  var *= (1.f / E_);
  float rs = rsqrtf(var + 1e-5f);
  float h1[E_];
#pragma unroll
  for (int e = 0; e < E_; e++) h1[e] = (tv[e] - mu) * rs * lnAg[e] + lnAb[e];

  // ---- D: FFN, 15 rows per part ----
  float g2p[E_];
#pragma unroll
  for (int e = 0; e < E_; e++) g2p[e] = 0.f;
  int jf0 = part * (FF_ / 8);
#pragma unroll
  for (int jj = 0; jj < FF_ / 8; jj++) {
    int j = jf0 + jj;
    float f = b1[j];
    DOT20G(f, W1, j, h1);
    f = fmaxf(f, 0.f);
    const float4* Wr = (const float4*)(W2t + j * 20);
#pragma unroll
    for (int g = 0; g < 5; g++) {
      float4 w4 = Wr[g];
      g2p[g * 4 + 0] += w4.x * f;
      g2p[g * 4 + 1] += w4.y * f;
      g2p[g * 4 + 2] += w4.z * f;
      g2p[g * 4 + 3] += w4.w * f;
    }
  }
  float4* scw = (float4*)(F->u.sc + tid * E_);
#pragma unroll
  for (int g = 0; g < 5; g++)
    scw[g] = make_float4(g2p[g * 4], g2p[g * 4 + 1], g2p[g * 4 + 2],
                         g2p[g * 4 + 3]);
  __syncthreads();

  // ---- E: reduce 8 partials + b2 + residual(h1), LN_B -> hv ----
  float g2[E_];
#pragma unroll
  for (int e = 0; e < E_; e++) g2[e] = b2[e] + h1[e];
#pragma unroll
  for (int pp = 0; pp < 8; pp++) {
    const float4* r = (const float4*)(F->u.sc + (pp * NPOS + p) * E_);
#pragma unroll
    for (int g = 0; g < 5; g++) {
      float4 v4 = r[g];
      g2[g * 4 + 0] += v4.x; g2[g * 4 + 1] += v4.y;
      g2[g * 4 + 2] += v4.z; g2[g * 4 + 3] += v4.w;
    }
  }
  float mu2 = 0.f;
#pragma unroll
  for (int e = 0; e < E_; e++) mu2 += g2[e];
  mu2 *= (1.f / E_);
  float var2 = 0.f;
#pragma unroll
  for (int e = 0; e < E_; e++) { float d = g2[e] - mu2; var2 += d * d; }
  var2 *= (1.f / E_);
  float rs2 = rsqrtf(var2 + 1e-5f);
#pragma unroll
  for (int e = 0; e < E_; e++)
    hv[e] = (g2[e] - mu2) * rs2 * lnBg[e] + lnBb[e];

  if (last) {
    __syncthreads();  // reduce reads done before reusing sc
#pragma unroll
    for (int j = 0; j < DEC_ / 8; j++) {
      int jj = part * (DEC_ / 8) + j;
      float a = f1b[jj];
      DOT20G(a, f1w, jj, hv);
      F->u.sc[p * 101 + jj] = fmaxf(a, 0.f);
    }
    __syncthreads();
    float d1[DEC_];
#pragma unroll
    for (int k = 0; k < DEC_; k++) d1[k] = F->u.sc[p * 101 + k];
#pragma unroll
    for (int j = 0; j < DEC_ / 8; j++) {
      int jj = part * (DEC_ / 8) + j;
      float a = f2b[jj];
      DOT40G(a, f2w, jj, d1);
      F->u.sc[p * 101 + 40 + jj] = fmaxf(a, 0.f);
    }
    __syncthreads();
    float d2[DEC_];
#pragma unroll
    for (int k = 0; k < DEC_; k++) d2[k] = F->u.sc[p * 101 + 40 + k];
    if (part < 5) {
#pragma unroll
      for (int j = 0; j < 4; j++) {
        int ee = part * 4 + j;
        float a = f3b[ee];
        DOT40G(a, f3w, ee, d2);
        F->u.sc[p * 101 + 80 + ee] = fmaxf(a, 0.f);
      }
    }
    __syncthreads();
    if (act && part == 0) {
      float z = f4b[0];
      const float* dv = F->u.sc + p * 101 + 80;
      DOT20G(z, f4w, 0, dv);
      out[pos] = 1.f / (1.f + __expf(-z));
    }
  }
}

// ---------------------------------------------------------------------------
// Persistent megakernel, 4 grid barriers total:
// phase0(conv+PE+W2t+M0) | fused0(+M1) | fused1(+M2) | fused2(+M3) | fused3+dec
// h never touches global memory (registers + 5KB LDS mirror).
// Mall is zeroed by a hipMemsetAsync BEFORE this kernel (stream-ordered),
// so phase-0's M0 atomics cannot race the zeroing.
// ---------------------------------------------------------------------------
__global__ __launch_bounds__(BLK_) void megakernel(
    const float* __restrict__ x, const float* __restrict__ cw,
    const float* __restrict__ Wv, const float* __restrict__ Wk,
    const float* __restrict__ Wq, const float* __restrict__ Wc,
    const float* __restrict__ bc, const float* __restrict__ lnAg,
    const float* __restrict__ lnAb, const float* __restrict__ W1,
    const float* __restrict__ b1, const float* __restrict__ W2,
    const float* __restrict__ b2, const float* __restrict__ lnBg,
    const float* __restrict__ lnBb,
    const float* __restrict__ f1w, const float* __restrict__ f1b,
    const float* __restrict__ f2w, const float* __restrict__ f2b,
    const float* __restrict__ f3w, const float* __restrict__ f3b,
    const float* __restrict__ f4w, const float* __restrict__ f4b,
    float* __restrict__ out, float* __restrict__ Mall,
    float* __restrict__ W2t) {
  __shared__ SUf S;
  const int tid = threadIdx.x;
  const int bid = blockIdx.x;
  const int p = tid & (NPOS - 1);
  const int part = tid >> 6;  // wave-uniform
  const int fb = bid / TPB_;
  const int l = (bid % TPB_) * NPOS + p;
  const bool act = l < L_;
  const int lc = act ? l : L_ - 1;
  const int pos = fb * L_ + lc;

  // ---- phase 0: W2t transpose (cache-bypass stores), conv+PE -> sh ----
  {
    int tg = bid * BLK_ + tid;
    if (tg < 4 * E_ * FF_) {
      int i = tg / (E_ * FF_), r = tg % (E_ * FF_);
      int e = r / FF_, j = r % FF_;
      __hip_atomic_store(&W2t[i * 2400 + j * E_ + e],
                         W2[i * 2400 + e * FF_ + j], __ATOMIC_RELAXED,
                         __HIP_MEMORY_SCOPE_AGENT);
    }
    if (part < H_) {
      const float* xr = x + fb * L_;
#pragma unroll
      for (int d = 0; d < 4; d++) {
        int e = part * 4 + d;
        const float* wr = cw + e * K_;
        float a0 = 0.f, a1 = 0.f;
#pragma unroll
        for (int k = 0; k < K_; k += 2) {
          int i0 = lc + k - PAD_, i1 = i0 + 1;
          float x0 = (i0 >= 0 && i0 < L_) ? xr[i0] : 0.f;
          float x1 = (i1 >= 0 && i1 < L_) ? xr[i1] : 0.f;
          a0 += x0 * wr[k];
          a1 += x1 * wr[k + 1];
        }
        double expo =
            (e & 1) ? (double)(e + 1) / (double)E_ : (double)e / (double)E_;
        double factor = pow(10000.0, -expo);
        double arg = (double)lc * factor;
        float pe = (e & 1) ? (float)cos(arg) : (float)sin(arg);
        S.sh[p * E_ + e] = (a0 + a1) + pe;
      }
    }
  }
  // M0 partials from this block's 64 keys (produce_M syncs internally)
  produce_M(p, part, fb, act, Wk, Wv, Mall, &S);
  grid_barrier();

  // residual h into registers (constant-indexed uses only)
  float hv[E_];
#pragma unroll
  for (int g = 0; g < 5; g++) {
    float4 h4 = *(const float4*)(S.sh + p * E_ + g * 4);
    hv[g * 4 + 0] = h4.x; hv[g * 4 + 1] = h4.y;
    hv[g * 4 + 2] = h4.z; hv[g * 4 + 3] = h4.w;
  }

  for (int layer = 0; layer < 4; layer++) {
    fused_phase(layer == 3, tid, p, part, fb, pos, act,
                Mall + layer * LSTRIDE, Wq + layer * 16, Wc + layer * 400,
                bc + layer * 20, lnAg + layer * 20, lnAb + layer * 20,
                W1 + layer * 2400, b1 + layer * 120, W2t + layer * 2400,
                b2 + layer * 20, lnBg + layer * 20, lnBb + layer * 20,
                f1w, f1b, f2w, f2b, f3w, f3b, f4w, f4b, out, hv, &S);
    if (layer < 3) {
      // refresh LDS h mirror (one writer per position; produce_M's first
      // __syncthreads orders it before the kk producers read sh)
      if (part == 0) {
#pragma unroll
        for (int g = 0; g < 5; g++)
          *(float4*)(S.sh + p * E_ + g * 4) =
              make_float4(hv[g * 4], hv[g * 4 + 1], hv[g * 4 + 2],
                          hv[g * 4 + 3]);
      }
      produce_M(p, part, fb, act, Wk + (layer + 1) * 16,
                Wv + (layer + 1) * 16, Mall + (layer + 1) * LSTRIDE, &S);
      grid_barrier();
    }
  }
}

// ---------------------------------------------------------------------------
extern "C" void kernel_launch(void* const* d_in, const int* in_sizes, int n_in,
                              void* d_out, int out_size, void* d_ws,
                              size_t ws_size, hipStream_t stream) {
  const float* x    = (const float*)d_in[0];
  const float* cw   = (const float*)d_in[1];
  const float* Wv   = (const float*)d_in[2];
  const float* Wk   = (const float*)d_in[3];
  const float* Wq   = (const float*)d_in[4];
  const float* Wc   = (const float*)d_in[5];
  const float* bc   = (const float*)d_in[6];
  const float* lnAg = (const float*)d_in[7];
  const float* lnAb = (const float*)d_in[8];
  const float* W1   = (const float*)d_in[9];
  const float* b1   = (const float*)d_in[10];
  const float* W2   = (const float*)d_in[11];
  const float* b2   = (const float*)d_in[12];
  const float* lnBg = (const float*)d_in[13];
  const float* lnBb = (const float*)d_in[14];
  const float* f1w  = (const float*)d_in[15];
  const float* f1b  = (const float*)d_in[16];
  const float* f2w  = (const float*)d_in[17];
  const float* f2b  = (const float*)d_in[18];
  const float* f3w  = (const float*)d_in[19];
  const float* f3b  = (const float*)d_in[20];
  const float* f4w  = (const float*)d_in[21];
  const float* f4b  = (const float*)d_in[22];
  float* out = (float*)d_out;

  // ws floats: Mall 4*LSTRIDE | W2t 4*2400
  float* ws = (float*)d_ws;
  float* Mall = ws;
  float* W2t = ws + 4 * LSTRIDE;

  // zero M before the kernel (stream-ordered -> no zero-vs-atomic race)
  hipMemsetAsync(Mall, 0, 4 * LSTRIDE * sizeof(float), stream);

  megakernel<<<dim3(GRID_), dim3(BLK_), 0, stream>>>(
      x, cw, Wv, Wk, Wq, Wc, bc, lnAg, lnAb, W1, b1, W2, b2, lnBg, lnBb,
      f1w, f1b, f2w, f2b, f3w, f3b, f4w, f4b, out, Mall, W2t);
}